// Round 13
// baseline (226.398 us; speedup 1.0000x reference)
//
#include <hip/hip_runtime.h>
#include <cstdint>
#include <cstddef>

// ---------------------------------------------------------------------------
// GenEdge R13 (resubmit — R11 bench never ran):
//   cvt    : R11/R12 fat-block coalesced version (unchanged).
//   edge   : 16-col waves (demand ~112 regs: A16 B48 acc12 S24 addr~12)
//            + R12 B-prefetch pipeline (loads for di+1 issued after MFMA,
//            before SAD chain) + launch_bounds(256,4): 128-reg budget fits
//            demand -> 4 waves/SIMD (R12 decode: 2nd arg SETS occupancy,
//            compiler fills budget; R10's spill was demand 176 > 128, not
//            the cap itself). + PACKED f32 SAD: rr-pairs as float2 ->
//            v_pk_fma/max on CDNA4; 18 -> 10 instrs/pair (sqrt scalar);
//            S0/S1 accumulate per-pair with single packed FMA.
//            VALU floor ~48us -> ~30us; 4 waves/SIMD -> VALUBusy 60-80%.
//   combine: sum halves, e=|gx|+|gy| (border zeroed), block-max -> atomicMax.
//   norm   : divide by global max.
// ---------------------------------------------------------------------------

typedef _Float16 half8 __attribute__((ext_vector_type(8)));
typedef float    f32x4 __attribute__((ext_vector_type(4)));
typedef float    f32x2 __attribute__((ext_vector_type(2)));

#define HW   400
#define NP   (HW*HW)
#define CCH  128
#define W16  416                 // padded width (26 groups of 16)
#define ROWE (W16*CCH)           // 53248 f16 elements per padded row
#define PAD  12
#define IEND 388                 // interior: [12, 388)
#define LDSF 132                 // padded f32 per pixel row (128+4)

// f16 cube layout per row: [pg(26)][ks(4)][q(4)][i(16)][j(8)] elements
// offset = pg*2048 + ks*512 + q*128 + i*8 + j

// ---------------- Phase 1: convert + normalize (coalesced, fat blocks) -----
__global__ void cvt_kernel(const float* __restrict__ cube,
                           _Float16* __restrict__ c16,
                           unsigned* __restrict__ gmax) {
  __shared__ float buf[16*LDSF];   // 8448 B
  __shared__ float part[16];
  int pg = blockIdx.x;          // 0..25 (pg 25 is all-pad)
  int rb = blockIdx.y;          // 0..39 -> rows rb*10 .. rb*10+9
  int t  = threadIdx.x;         // 0..255
  if (pg == 0 && rb == 0 && t == 0) *gmax = 0u;  // every call (re-poisoned ws)
  int pa = t >> 5, oa = (t & 31)*4;
  int p  = t >> 4, k  = t & 15;
  int i  = t & 15, cb = t >> 4;
  for (int r = rb*10; r < rb*10 + 10; ++r) {
    if (pg == 25) {             // all 16 pixels are padding -> zero output
      half8 hz;
      #pragma unroll
      for (int j = 0; j < 8; ++j) hz[j] = (_Float16)0.f;
      *(half8*)(c16 + (size_t)r*ROWE + 25*2048 + t*8) = hz;
      continue;                 // block-uniform branch: barrier-safe
    }
    // coalesced read: 2048 consecutive floats (16 pixels x 128 ch)
    const float4* src4 = (const float4*)(cube + ((size_t)(r*HW + pg*16))*CCH);
    float4 fa = src4[t];
    float4 fb = src4[t + 256];
    __syncthreads();            // WAR: previous iteration's readers done
    *(float4*)&buf[pa*LDSF + oa]     = fa;
    *(float4*)&buf[(8+pa)*LDSF + oa] = fb;
    __syncthreads();
    const float4* pr = (const float4*)&buf[p*LDSF + k*8];
    float4 x0 = pr[0], x1 = pr[1];
    float ss = x0.x*x0.x + x0.y*x0.y + x0.z*x0.z + x0.w*x0.w
             + x1.x*x1.x + x1.y*x1.y + x1.z*x1.z + x1.w*x1.w;
    ss += __shfl_xor(ss, 1);
    ss += __shfl_xor(ss, 2);
    ss += __shfl_xor(ss, 4);
    ss += __shfl_xor(ss, 8);
    if (k == 0) part[p] = ss;
    __syncthreads();
    float tot = part[i];
    float sc = (tot > 0.f) ? rsqrtf(tot) : 0.f;
    const float4* vp = (const float4*)&buf[i*LDSF + cb*8];
    float4 v0 = vp[0], v1 = vp[1];
    half8 hv;
    hv[0] = (_Float16)(v0.x*sc); hv[1] = (_Float16)(v0.y*sc);
    hv[2] = (_Float16)(v0.z*sc); hv[3] = (_Float16)(v0.w*sc);
    hv[4] = (_Float16)(v1.x*sc); hv[5] = (_Float16)(v1.y*sc);
    hv[6] = (_Float16)(v1.z*sc); hv[7] = (_Float16)(v1.w*sc);
    *(half8*)(c16 + (size_t)r*ROWE + pg*2048 + t*8) = hv;
  }
}

// ---------------- Phase 2: banded MFMA + packed SAD (pipelined) ------------
__global__ __launch_bounds__(256, 4) void edge_kernel(
    const _Float16* __restrict__ c16,
    float* __restrict__ gxp, float* __restrict__ gyp) {
  // 4512 blocks = 8 XCDs x 564; per XCD contiguous row band.
  // Block: 4 waves, wave wv -> wb = wbq*4 + wv (16-col tile), SAME row+half.
  const int id  = blockIdx.x;
  const int g   = (id & 7)*564 + (id >> 3);
  const int row = g / 12;                // 0..375
  const int rem = g - row*12;            // wbq*2 + half
  const int half = rem & 1;              // di half
  const int wbq  = rem >> 1;             // 0..5
  const int h   = row + PAD;             // 12..387
  const int wv  = threadIdx.x >> 6;      // wave 0..3
  const int wb  = wbq*4 + wv;            // 0..23
  const int l   = threadIdx.x & 63;
  const int c   = l & 15, q = l >> 4;
  const int w0  = PAD + 16*wb;           // first center col of tile

  // A-frags: center pixels w0..w0+15 of row h.  A[m=lane&15][k=q*8+j]
  half8 A[4];
  {
    int px = w0 + c;                     // <= 395 < 400
    const _Float16* pA = c16 + (size_t)h*ROWE + (px >> 4)*2048 + q*128 + (px & 15)*8;
    #pragma unroll
    for (int ks = 0; ks < 4; ++ks)
      A[ks] = *(const half8*)(pA + ks*512);
  }

  const float cq = (float)(c - 4*q);     // dj-12 = 16d - 12 - rr + (c-4q)

  // factored accumulators, PACKED over rr pairs: S[d][pp] covers rr=2*pp+{0,1}
  f32x2 S0[3][2], S1[3][2];
  #pragma unroll
  for (int d = 0; d < 3; ++d)
    #pragma unroll
    for (int pp = 0; pp < 2; ++pp) {
      S0[d][pp] = (f32x2){0.f, 0.f};
      S1[d][pp] = (f32x2){0.f, 0.f};
    }

  const f32x4 z4 = {0.f, 0.f, 0.f, 0.f};
  const f32x2 one2  = {1.f, 1.f};
  const f32x2 zero2 = {0.f, 0.f};
  const f32x2 pc3 = {-0.0187292994f, -0.0187292994f};
  const f32x2 pc2 = { 0.0742610134f,  0.0742610134f};
  const f32x2 pc1 = {-0.2121143967f, -0.2121143967f};
  const f32x2 pc0 = { 1.5707287572f,  1.5707287572f};

  const _Float16* bBase = c16 + wb*2048 + (size_t)l*8;
  // di=12 belongs to BOTH halves at weight 0.5.
  const int diLo = half ? 12 : 0;
  const int diHi = half ? 25 : 13;

  // B frags for the CURRENT di; refilled for di+1 after the MFMA phase and
  // before the SAD chain (software pipeline, single-buffered).
  half8 B[3][4];                         // [group][ks], 48 VGPRs
  {
    const _Float16* rowB = bBase + (size_t)(h + diLo - PAD)*ROWE;
    #pragma unroll
    for (int gg = 0; gg < 3; ++gg)
      #pragma unroll
      for (int ks = 0; ks < 4; ++ks)
        B[gg][ks] = *(const half8*)(rowB + gg*2048 + ks*512);
  }

  #pragma unroll 1
  for (int di = diLo; di < diHi; ++di) {
    // ---- MFMA phase (consumes B) ----
    f32x4 acc[3];
    #pragma unroll
    for (int ks = 0; ks < 4; ++ks) {
      if (ks == 0) {
        acc[0] = __builtin_amdgcn_mfma_f32_16x16x32_f16(A[0], B[0][0], z4, 0,0,0);
        acc[1] = __builtin_amdgcn_mfma_f32_16x16x32_f16(A[0], B[1][0], z4, 0,0,0);
        acc[2] = __builtin_amdgcn_mfma_f32_16x16x32_f16(A[0], B[2][0], z4, 0,0,0);
      } else {
        acc[0] = __builtin_amdgcn_mfma_f32_16x16x32_f16(A[ks], B[0][ks], acc[0], 0,0,0);
        acc[1] = __builtin_amdgcn_mfma_f32_16x16x32_f16(A[ks], B[1][ks], acc[1], 0,0,0);
        acc[2] = __builtin_amdgcn_mfma_f32_16x16x32_f16(A[ks], B[2][ks], acc[2], 0,0,0);
      }
    }

    // ---- prefetch B for di+1 (L2 latency hides under the SAD chain) ----
    if (di + 1 < diHi) {
      const _Float16* rowB = bBase + (size_t)(h + di + 1 - PAD)*ROWE;
      #pragma unroll
      for (int gg = 0; gg < 3; ++gg)
        #pragma unroll
        for (int ks = 0; ks < 4; ++ks)
          B[gg][ks] = *(const half8*)(rowB + gg*2048 + ks*512);
    }

    // ---- packed SAD phase (consumes acc) ----
    const float ii  = (float)((di <= 12) ? di : 24 - di);
    const float w0s = (di == 12) ? 0.5f : 1.0f;
    const float w1s = w0s * ii;
    const f32x2 w0v = {w0s, w0s};
    const f32x2 w1v = {w1s, w1s};

    #pragma unroll
    for (int d = 0; d < 3; ++d)
      #pragma unroll
      for (int pp = 0; pp < 2; ++pp) {
        f32x2 x2 = { acc[d][2*pp], acc[d][2*pp + 1] };  // consecutive VGPRs
        f32x2 t2 = one2 - x2;
        t2 = __builtin_elementwise_max(t2, zero2);
        f32x2 s2;
        s2.x = __builtin_amdgcn_sqrtf(t2.x);
        s2.y = __builtin_amdgcn_sqrtf(t2.y);
        f32x2 p2 = __builtin_elementwise_fma(x2, pc3, pc2);
        p2 = __builtin_elementwise_fma(p2, x2, pc1);
        p2 = __builtin_elementwise_fma(p2, x2, pc0);
        f32x2 sad2 = s2 * p2;                           // acos(x), |err|<7e-5
        S0[d][pp] = __builtin_elementwise_fma(sad2, w0v, S0[d][pp]);
        S1[d][pp] = __builtin_elementwise_fma(sad2, w1v, S1[d][pp]);
      }
  }

  // epilogue: apply di-invariant weights once.
  //   kx = p + sg*ii            -> gx = p*S0 + sg*S1
  //   ky = s_h*(12 + mnj - ii)  -> gy = s_h*((12+mnj)*S0 - S1)
  const float s_h = half ? 1.0f : -1.0f;
  float gx[4], gy[4];
  #pragma unroll
  for (int rr = 0; rr < 4; ++rr) { gx[rr] = 0.f; gy[rr] = 0.f; }

  #pragma unroll
  for (int d = 0; d < 3; ++d)
    #pragma unroll
    for (int rr = 0; rr < 4; ++rr) {
      float p   = cq + (float)(16*d - 12 - rr);   // dj - 12 (integer)
      float ap  = fabsf(p);
      float mnj = 12.0f - ap;                     // >=0 iff |dj-12|<=12
      bool  ok  = mnj >= 0.0f;
      float sg  = fminf(fmaxf(p, -1.0f), 1.0f);   // sgn(p)
      float wy  = 12.0f + mnj;
      float s0 = S0[d][rr >> 1][rr & 1];
      float s1 = S1[d][rr >> 1][rr & 1];
      gx[rr] += ok ? fmaf(sg, s1, p*s0) : 0.0f;
      gy[rr] += ok ? s_h*fmaf(wy, s0, -s1) : 0.0f;
    }

  // reduce over c (lane bits 0..3); writer lanes c == rr store partials
  const int hoff = half*NP + h*HW;
  #pragma unroll
  for (int rr = 0; rr < 4; ++rr) {
    float sgx = gx[rr], sgy = gy[rr];
    #pragma unroll
    for (int m = 1; m < 16; m <<= 1) {
      sgx += __shfl_xor(sgx, m);
      sgy += __shfl_xor(sgy, m);
    }
    if (c == rr) {
      int w = w0 + 4*q + rr;             // <= 395, disjoint across waves
      gxp[hoff + w] = sgx;
      gyp[hoff + w] = sgy;
    }
  }
}

// ---------------- Phase 3a: combine halves + global max ----------------
__global__ void combine_kernel(float* __restrict__ gxp,
                               const float* __restrict__ gyp,
                               unsigned* __restrict__ gmax) {
  __shared__ float wm[4];
  int idx = blockIdx.x*256 + threadIdx.x;      // 625*256 = NP exactly
  int hh = idx / HW;
  int ww = idx - hh*HW;
  float e = 0.f;
  if (hh >= PAD && hh < IEND && ww >= PAD && ww < IEND)
    e = fabsf(gxp[idx] + gxp[NP + idx]) + fabsf(gyp[idx] + gyp[NP + idx]);
  gxp[idx] = e;                                // edge buffer aliases gxp[0]
  float m = e;
  #pragma unroll
  for (int off = 1; off < 64; off <<= 1) m = fmaxf(m, __shfl_xor(m, off));
  if ((threadIdx.x & 63) == 0) wm[threadIdx.x >> 6] = m;
  __syncthreads();
  if (threadIdx.x == 0) {
    float mm = fmaxf(fmaxf(wm[0], wm[1]), fmaxf(wm[2], wm[3]));
    atomicMax(gmax, __float_as_uint(mm));      // e >= 0: uint order ok
  }
}

// ---------------- Phase 3b: normalize ----------------
__global__ void norm_kernel(const float* __restrict__ edge,
                            const unsigned* __restrict__ gmax,
                            float* __restrict__ out) {
  int idx = blockIdx.x*256 + threadIdx.x;
  float mv = __uint_as_float(*gmax);
  out[idx] = edge[idx] / mv;                   // border already 0
}

// ---------------- launch ----------------
extern "C" void kernel_launch(void* const* d_in, const int* in_sizes, int n_in,
                              void* d_out, int out_size, void* d_ws, size_t ws_size,
                              hipStream_t stream) {
  const float* cube = (const float*)d_in[0];   // (1,400,400,128) f32
  char* ws = (char*)d_ws;
  _Float16* c16  = (_Float16*)(ws);                     // 42,598,400 B
  float*    gxp  = (float*)(ws + 42598400);             // 2*NP floats
  float*    gyp  = (float*)(ws + 42598400 + 8*NP);      // 2*NP floats
  unsigned* gmax = (unsigned*)(ws + 42598400 + 16*NP);  // 4 B  (~45.2 MB total)

  cvt_kernel<<<dim3(26, 40), 256, 0, stream>>>(cube, c16, gmax);
  edge_kernel<<<4512, 256, 0, stream>>>(c16, gxp, gyp);
  combine_kernel<<<NP/256, 256, 0, stream>>>(gxp, gyp, gmax);
  norm_kernel<<<NP/256, 256, 0, stream>>>(gxp, gmax, (float*)d_out);
}